// Round 1
// baseline (552.815 us; speedup 1.0000x reference)
//
#include <hip/hip_runtime.h>

// ---------------------------------------------------------------------------
// control_solver: 100-step SDE rollout of a 5-layer MLP over 4096 rows.
// Design (R1):
//  - 256 blocks x 512 threads (8 waves), each block owns 16 batch rows for the
//    whole time loop (batch rows are independent -> no grid sync needed).
//  - bf16 MFMA 16x16x32, f32 accumulation. Weights pre-packed (pack_w kernel)
//    into per-lane B-fragment layout [tile][kiter][lane][8] in d_ws.
//  - W1,W2,W3,Wout register-resident per wave (tiles {w, w+8} of 13; Wout tile w
//    of 7). W0 streamed from L2 each step (53KB/block/step).
//  - Activations in LDS in A-fragment layout [kiter][lane(64)][8] bf16, so all
//    fragment reads are ds_read_b128. S, err carried in f32 registers of the
//    lanes owning the final-layer C fragment.
// ---------------------------------------------------------------------------

typedef __attribute__((ext_vector_type(8))) short  bf16x8;
typedef __attribute__((ext_vector_type(4))) float  f32x4;

#define MFMA16(A,B,C) __builtin_amdgcn_mfma_f32_16x16x32_bf16((A),(B),(C),0,0,0)

#define NBATCH 4096
#define NDIM   100
#define NT     101
#define NWID   200

// packed weight layout (ushort element offsets inside d_ws)
#define E0   (13*4*512)        // W0: 13 tiles x 4 kiters x 64 lanes x 8
#define E1   (13*7*512)        // W1/2/3: 13 tiles x 7 kiters
#define EOUTW (7*7*512)        // Wout: 7 tiles x 7 kiters
#define OFF0 0
#define OFF1 (E0)
#define OFF2 (OFF1+E1)
#define OFF3 (OFF2+E1)
#define OFF4 (OFF3+E1)
#define TOTE (OFF4+EOUTW)      // 191488 ushorts = 382976 B

__device__ __forceinline__ unsigned short f2bf(float x){
  unsigned u = __float_as_uint(x);
  unsigned r = (u + 0x7fffu + ((u >> 16) & 1u)) >> 16;   // RNE
  return (unsigned short)r;
}

__device__ __forceinline__ bf16x8 zero8(){
  bf16x8 z;
#pragma unroll
  for (int e = 0; e < 8; ++e) z[e] = 0;
  return z;
}

// A/activation fragment store: element (row m, feature k) -> LDS slot
__device__ __forceinline__ void st_act(unsigned short* buf, int m, int k, unsigned short v){
  buf[(((k >> 5) * 64) + (((k >> 3) & 3) * 16) + m) * 8 + (k & 7)] = v;
}

// ---------------------------------------------------------------------------
// Pre-pack weights (runs every launch; d_ws is re-poisoned by the harness).
// fragment element: value = W[k][n], n = tile*16 + (lane&15),
//                   k = kiter*32 + (lane>>4)*8 + j   (zero padded)
// ---------------------------------------------------------------------------
__global__ void pack_w(const float* __restrict__ W0, const float* __restrict__ W1,
                       const float* __restrict__ W2, const float* __restrict__ W3,
                       const float* __restrict__ Wo, unsigned short* __restrict__ out){
  int idx = blockIdx.x * 256 + threadIdx.x;
  if (idx >= TOTE) return;
  const float* src; int Kt, Nt, KI, local;
  if      (idx < OFF1){ src = W0; Kt = 101; Nt = 200; KI = 4; local = idx - OFF0; }
  else if (idx < OFF2){ src = W1; Kt = 200; Nt = 200; KI = 7; local = idx - OFF1; }
  else if (idx < OFF3){ src = W2; Kt = 200; Nt = 200; KI = 7; local = idx - OFF2; }
  else if (idx < OFF4){ src = W3; Kt = 200; Nt = 200; KI = 7; local = idx - OFF3; }
  else                { src = Wo; Kt = 200; Nt = 100; KI = 7; local = idx - OFF4; }
  int per_tile = KI * 512;
  int tile = local / per_tile;
  int rem  = local - tile * per_tile;
  int kit  = rem >> 9;
  int within = rem & 511;
  int lane = within >> 3, j = within & 7;
  int n = tile * 16 + (lane & 15);
  int k = kit * 32 + (lane >> 4) * 8 + j;
  unsigned short v = 0;
  if (k < Kt && n < Nt) v = f2bf(src[k * Nt + n]);
  out[idx] = v;
}

// ---------------------------------------------------------------------------
// Main persistent solver kernel.
// ---------------------------------------------------------------------------
__global__ __launch_bounds__(512, 2) void solver(
    const float* __restrict__ S0,  const float* __restrict__ tg,
    const float* __restrict__ dW,  const unsigned short* __restrict__ Wp,
    const float* __restrict__ b0g, const float* __restrict__ b1g,
    const float* __restrict__ b2g, const float* __restrict__ b3g,
    const float* __restrict__ bog, float* __restrict__ outp)
{
  __shared__ unsigned short sm_t0[2048];   // L0 input  [4 kiters][64][8]
  __shared__ unsigned short sm_a[3584];    // hidden act ping [7][64][8]
  __shared__ unsigned short sm_b[3584];    // hidden act pong
  __shared__ float sbias[944];             // b0,b1,b2,b3 (208 ea, pad 0) + bout (112)
  float* sb0 = sbias;       float* sb1 = sbias + 208;
  float* sb2 = sbias + 416; float* sb3 = sbias + 624;
  float* sbo = sbias + 832;

  const int tid  = threadIdx.x;
  const int lane = tid & 63;
  const int w    = tid >> 6;         // wave id 0..7
  const int q    = lane >> 4;        // quad 0..3
  const int mr   = lane & 15;
  const int blk  = blockIdx.x;
  const bool t1ok = (w < 5);         // second N-tile (w+8) valid (tiles 8..12)
  const bool act4 = (w < 7);         // owns an output-layer tile

  // ---- init LDS ----
  for (int i = tid; i < 1024; i += 512) ((unsigned*)sm_t0)[i] = 0u;
  for (int i = tid; i < 1792; i += 512) ((unsigned*)sm_a )[i] = 0u;
  for (int i = tid; i < 1792; i += 512) ((unsigned*)sm_b )[i] = 0u;
  for (int i = tid; i < 208; i += 512){
    float z0 = (i < 200) ? b0g[i] : 0.f; sb0[i] = z0;
    float z1 = (i < 200) ? b1g[i] : 0.f; sb1[i] = z1;
    float z2 = (i < 200) ? b2g[i] : 0.f; sb2[i] = z2;
    float z3 = (i < 200) ? b3g[i] : 0.f; sb3[i] = z3;
  }
  for (int i = tid; i < 112; i += 512) sbo[i] = (i < 100) ? bog[i] : 0.f;

  // ---- register-resident weights: W1,W2,W3 tiles {w, w+8}; Wout tile w ----
  bf16x8 w1f[2][7], w2f[2][7], w3f[2][7], wo_f[7];
#pragma unroll
  for (int k = 0; k < 7; ++k){
    w1f[0][k] = *(const bf16x8*)(Wp + OFF1 + ((w * 7 + k) * 64 + lane) * 8);
    w2f[0][k] = *(const bf16x8*)(Wp + OFF2 + ((w * 7 + k) * 64 + lane) * 8);
    w3f[0][k] = *(const bf16x8*)(Wp + OFF3 + ((w * 7 + k) * 64 + lane) * 8);
    if (t1ok){
      w1f[1][k] = *(const bf16x8*)(Wp + OFF1 + (((w + 8) * 7 + k) * 64 + lane) * 8);
      w2f[1][k] = *(const bf16x8*)(Wp + OFF2 + (((w + 8) * 7 + k) * 64 + lane) * 8);
      w3f[1][k] = *(const bf16x8*)(Wp + OFF3 + (((w + 8) * 7 + k) * 64 + lane) * 8);
    } else {
      w1f[1][k] = zero8(); w2f[1][k] = zero8(); w3f[1][k] = zero8();
    }
    wo_f[k] = act4 ? *(const bf16x8*)(Wp + OFF4 + ((w * 7 + k) * 64 + lane) * 8)
                   : zero8();
  }

  // ---- state: S, err in registers of the output-fragment-owning lanes ----
  const int cc  = w * 16 + mr;            // output column (valid when act4)
  const bool cok = act4 && (cc < 100);
  float Sr[4], Er[4];
#pragma unroll
  for (int i = 0; i < 4; ++i){
    int b = blk * 16 + q * 4 + i;
    Sr[i] = cok ? S0[b * NDIM + cc] : 0.f;
    Er[i] = 0.f;
  }
  if (act4){
#pragma unroll
    for (int i = 0; i < 4; ++i)
      st_act(sm_t0, q * 4 + i, 1 + cc, f2bf(Sr[i]));   // S into L0 A-fragment
  }

  const float hh = tg[1] - tg[0];
  const float sq = sqrtf(hh);

#define HIDDEN_LAYER(SRC, DST, WF, SB)                                        \
  { f32x4 accA = {0.f,0.f,0.f,0.f}, accB = {0.f,0.f,0.f,0.f};                 \
    _Pragma("unroll")                                                         \
    for (int k = 0; k < 7; ++k){                                              \
      bf16x8 a = *(const bf16x8*)((SRC) + (k * 64 + lane) * 8);               \
      accA = MFMA16(a, WF[0][k], accA);                                       \
      if (t1ok) accB = MFMA16(a, WF[1][k], accB);                             \
    }                                                                         \
    { int c0 = w * 16 + mr;                                                   \
      _Pragma("unroll")                                                       \
      for (int i = 0; i < 4; ++i){                                            \
        float v = accA[i] + SB[c0]; v = fmaxf(v, 0.f);                        \
        st_act(DST, q * 4 + i, c0, f2bf(v)); } }                              \
    if (t1ok){ int c1 = (w + 8) * 16 + mr;                                    \
      _Pragma("unroll")                                                       \
      for (int i = 0; i < 4; ++i){                                            \
        float v = accB[i] + SB[c1]; v = fmaxf(v, 0.f);                        \
        st_act(DST, q * 4 + i, c1, f2bf(v)); } }                              \
  }

  // ---- time loop ----
  for (int t = 0; t < 100; ++t){
    if (tid < 16) sm_t0[tid * 8] = f2bf(tg[t]);       // feature k=0 = t
    float dwr[4];
#pragma unroll
    for (int i = 0; i < 4; ++i){                       // prefetch dW for step t
      int b = blk * 16 + q * 4 + i;
      int d = cok ? cc : 0;
      dwr[i] = act4 ? dW[b * 10100 + t * 100 + d] : 0.f;
    }
    __syncthreads();                                    // (1) S-frag + t visible

    // ---- L0: [t,S] (K=128) @ W0 (streamed from L2) -> sm_a
    {
      f32x4 acc0 = {0.f,0.f,0.f,0.f}, acc1 = {0.f,0.f,0.f,0.f};
#pragma unroll
      for (int k = 0; k < 4; ++k){
        bf16x8 a  = *(const bf16x8*)(sm_t0 + (k * 64 + lane) * 8);
        bf16x8 bA = *(const bf16x8*)(Wp + OFF0 + ((w * 4 + k) * 64 + lane) * 8);
        acc0 = MFMA16(a, bA, acc0);
        if (t1ok){
          bf16x8 bB = *(const bf16x8*)(Wp + OFF0 + (((w + 8) * 4 + k) * 64 + lane) * 8);
          acc1 = MFMA16(a, bB, acc1);
        }
      }
      { int c0 = w * 16 + mr;
#pragma unroll
        for (int i = 0; i < 4; ++i){
          float v = acc0[i] + sb0[c0]; v = fmaxf(v, 0.f);
          st_act(sm_a, q * 4 + i, c0, f2bf(v)); } }
      if (t1ok){ int c1 = (w + 8) * 16 + mr;
#pragma unroll
        for (int i = 0; i < 4; ++i){
          float v = acc1[i] + sb0[c1]; v = fmaxf(v, 0.f);
          st_act(sm_a, q * 4 + i, c1, f2bf(v)); } }
    }
    __syncthreads();                                    // (2)
    HIDDEN_LAYER(sm_a, sm_b, w1f, sb1)
    __syncthreads();                                    // (3)
    HIDDEN_LAYER(sm_b, sm_a, w2f, sb2)
    __syncthreads();                                    // (4)
    HIDDEN_LAYER(sm_a, sm_b, w3f, sb3)
    __syncthreads();                                    // (5)

    // ---- L4: h3 @ Wout (regs) -> u; update S, err; write S-frag for next step
    if (act4){
      f32x4 a4 = {0.f,0.f,0.f,0.f};
#pragma unroll
      for (int k = 0; k < 7; ++k){
        bf16x8 a = *(const bf16x8*)(sm_b + (k * 64 + lane) * 8);
        a4 = MFMA16(a, wo_f[k], a4);
      }
#pragma unroll
      for (int i = 0; i < 4; ++i){
        float u = a4[i] + sbo[cc];                     // u==0 for pad cols (cc>=100)
        Er[i] += u * u * hh;
        Sr[i] += u * (hh + sq * dwr[i]);
        st_act(sm_t0, q * 4 + i, 1 + cc, f2bf(Sr[i]));
      }
    }
  }

  // ---- output: err + S^2
  if (cok){
#pragma unroll
    for (int i = 0; i < 4; ++i){
      int b = blk * 16 + q * 4 + i;
      outp[b * NDIM + cc] = Er[i] + Sr[i] * Sr[i];
    }
  }
#undef HIDDEN_LAYER
}

extern "C" void kernel_launch(void* const* d_in, const int* in_sizes, int n_in,
                              void* d_out, int out_size, void* d_ws, size_t ws_size,
                              hipStream_t stream) {
  const float* S0  = (const float*)d_in[0];
  const float* tg  = (const float*)d_in[1];
  const float* dW  = (const float*)d_in[2];
  const float* W0  = (const float*)d_in[3];
  const float* b0  = (const float*)d_in[4];
  const float* W1  = (const float*)d_in[5];
  const float* b1  = (const float*)d_in[6];
  const float* W2  = (const float*)d_in[7];
  const float* b2  = (const float*)d_in[8];
  const float* W3  = (const float*)d_in[9];
  const float* b3  = (const float*)d_in[10];
  const float* Wo  = (const float*)d_in[11];
  const float* bo  = (const float*)d_in[12];
  unsigned short* Wp = (unsigned short*)d_ws;   // 382976 B used

  pack_w<<<(TOTE + 255) / 256, 256, 0, stream>>>(W0, W1, W2, W3, Wo, Wp);
  solver<<<256, 512, 0, stream>>>(S0, tg, dW, Wp, b0, b1, b2, b3, bo, (float*)d_out);
}

// Round 2
// 456.168 us; speedup vs baseline: 1.2119x; 1.2119x over previous
//
#include <hip/hip_runtime.h>

// ---------------------------------------------------------------------------
// R2: transposed (feature-major) formulation.
//  D = A*B with A = W^T tile fragments (VGPR-resident), B = activation
//  fragments (LDS, row-major [row][feat], stride 232 ushorts).
//  C/D: lane(q,mr) holds 4 consecutive out-features (tile*16+q*4+i) of batch
//  row mr -> one aligned ds_write_b64 per tile; next layer reads b128.
//  Biases folded into weights as K-row with activation==1.0:
//    W0 packed rows: k<100 -> W0[1+k][n]; k==100 -> W0[0][n] (t); k==101 -> b0.
//    W1/2/3 rows:    k<200 -> W[k][n];    k==200 -> b.
//    Wout rows:      k<200 -> Wo[k][n];   k==200 -> bo.
//  256 blocks x 512 threads (8 waves), 16 rows/block, 100 steps in-kernel.
//  W1,W2,W3 tiles {w, w+8(w<5)} + Wout tile w (w<7) in registers (~196 VGPR);
//  W0 staged to LDS once.  amdgpu_waves_per_eu(2,2) -> 256-VGPR budget.
// ---------------------------------------------------------------------------

typedef __attribute__((ext_vector_type(8))) short  bf16x8;
typedef __attribute__((ext_vector_type(4))) float  f32x4;

#define MFMA16(A,B,C) __builtin_amdgcn_mfma_f32_16x16x32_bf16((A),(B),(C),0,0,0)

#define FS 232                     // activation row stride (ushorts); 464B = 29*16

// packed weight layout (ushort element offsets inside d_ws)
#define OFF1 26624                 // W0: 13 tiles x 4 kit x 512
#define E1   46592                 // W1/2/3: 13 tiles x 7 kit x 512
#define OFF2 (OFF1+E1)
#define OFF3 (OFF2+E1)
#define OFF4 (OFF3+E1)
#define TOTE (OFF4+7*7*512)        // 191488 ushorts = 382976 B

__device__ __forceinline__ unsigned short f2bf(float x){
  unsigned u = __float_as_uint(x);
  return (unsigned short)((u + 0x7fffu + ((u >> 16) & 1u)) >> 16);  // RNE
}

// ---------------------------------------------------------------------------
__global__ void pack_w(const float* __restrict__ W0, const float* __restrict__ b0,
                       const float* __restrict__ W1, const float* __restrict__ b1,
                       const float* __restrict__ W2, const float* __restrict__ b2,
                       const float* __restrict__ W3, const float* __restrict__ b3,
                       const float* __restrict__ Wo, const float* __restrict__ bo,
                       unsigned short* __restrict__ out){
  int idx = blockIdx.x * 256 + threadIdx.x;
  if (idx >= TOTE) return;
  const float *Ws, *bs; int KI, NT, local, isw0 = 0;
  if      (idx < OFF1){ Ws = W0; bs = b0; KI = 4; NT = 200; local = idx;        isw0 = 1; }
  else if (idx < OFF2){ Ws = W1; bs = b1; KI = 7; NT = 200; local = idx - OFF1; }
  else if (idx < OFF3){ Ws = W2; bs = b2; KI = 7; NT = 200; local = idx - OFF2; }
  else if (idx < OFF4){ Ws = W3; bs = b3; KI = 7; NT = 200; local = idx - OFF3; }
  else                { Ws = Wo; bs = bo; KI = 7; NT = 100; local = idx - OFF4; }
  int per_tile = KI * 512;
  int tile = local / per_tile;
  int rem  = local - tile * per_tile;
  int kit  = rem >> 9;
  int within = rem & 511;
  int ln = within >> 3, j = within & 7;
  int n = tile * 16 + (ln & 15);          // out-feature
  int k = kit * 32 + (ln >> 4) * 8 + j;   // in-feature (incl. bias row)
  float v = 0.f;
  if (n < NT){
    if (isw0){
      if      (k < 100)  v = Ws[(1 + k) * 200 + n];   // S dims
      else if (k == 100) v = Ws[n];                   // t row
      else if (k == 101) v = bs[n];                   // bias row
    } else {
      if      (k < 200)  v = Ws[k * NT + n];
      else if (k == 200) v = bs[n];                   // bias row
    }
  }
  out[idx] = f2bf(v);
}

// ---------------------------------------------------------------------------
__global__ __launch_bounds__(512, 2) __attribute__((amdgpu_waves_per_eu(2, 2)))
void solver(const float* __restrict__ S0, const float* __restrict__ tg,
            const float* __restrict__ dW, const unsigned short* __restrict__ Wp,
            float* __restrict__ outp)
{
  __shared__ __attribute__((aligned(16))) unsigned short sW0[26624];  // 53 KB
  __shared__ __attribute__((aligned(16))) unsigned short sIn[16 * FS];
  __shared__ __attribute__((aligned(16))) unsigned short sA [16 * FS];
  __shared__ __attribute__((aligned(16))) unsigned short sB [16 * FS];

  const int tid  = threadIdx.x;
  const int lane = tid & 63;
  const int w    = tid >> 6;          // wave 0..7
  const int q    = lane >> 4;
  const int mr   = lane & 15;         // batch row within block
  const int blk  = blockIdx.x;
  const bool has2   = (w < 5);        // second tile (w+8) of 13
  const bool hasOut = (w < 7);        // owns an output tile
  const int t0 = w, t1 = w + 8;
  const int f0 = w * 16 + q * 4;      // L4 / state feature base
  const bool fvalid = hasOut && (f0 <= 96);
  const int rowoff = mr * FS;

  // ---- init LDS: zero act buffers, set bias-activation 1.0 rows ----
  for (int i = tid; i < 16 * FS / 2; i += 512){
    ((unsigned*)sIn)[i] = 0u; ((unsigned*)sA)[i] = 0u; ((unsigned*)sB)[i] = 0u;
  }
  for (int i = tid; i < 3328; i += 512)            // stage W0 (13*4*512 ushorts)
    ((uint4*)sW0)[i] = ((const uint4*)Wp)[i];
  if (tid < 16){
    sIn[tid * FS + 101] = 0x3F80;                  // bf16(1.0) -> b0 row
    sA [tid * FS + 200] = 0x3F80;                  // -> b1/b3 row
    sB [tid * FS + 200] = 0x3F80;                  // -> b2/bo row
  }

  // ---- register-resident weights ----
  bf16x8 w1f[2][7], w2f[2][7], w3f[2][7], wo_f[7];
#pragma unroll
  for (int k = 0; k < 7; ++k){
    w1f[0][k] = *(const bf16x8*)(Wp + OFF1 + ((t0 * 7 + k) * 64 + lane) * 8);
    w2f[0][k] = *(const bf16x8*)(Wp + OFF2 + ((t0 * 7 + k) * 64 + lane) * 8);
    w3f[0][k] = *(const bf16x8*)(Wp + OFF3 + ((t0 * 7 + k) * 64 + lane) * 8);
  }
  if (has2){
#pragma unroll
    for (int k = 0; k < 7; ++k){
      w1f[1][k] = *(const bf16x8*)(Wp + OFF1 + ((t1 * 7 + k) * 64 + lane) * 8);
      w2f[1][k] = *(const bf16x8*)(Wp + OFF2 + ((t1 * 7 + k) * 64 + lane) * 8);
      w3f[1][k] = *(const bf16x8*)(Wp + OFF3 + ((t1 * 7 + k) * 64 + lane) * 8);
    }
  }
  if (hasOut){
#pragma unroll
    for (int k = 0; k < 7; ++k)
      wo_f[k] = *(const bf16x8*)(Wp + OFF4 + ((w * 7 + k) * 64 + lane) * 8);
  }

  // ---- state: S, err for features f0..f0+3 of row mr ----
  float Sr[4] = {0.f, 0.f, 0.f, 0.f}, Er[4] = {0.f, 0.f, 0.f, 0.f};
  if (fvalid){
    f32x4 s0v = *(const f32x4*)(S0 + (blk * 16 + mr) * 100 + f0);
#pragma unroll
    for (int i = 0; i < 4; ++i) Sr[i] = s0v[i];
    unsigned lo = (unsigned)f2bf(Sr[0]) | ((unsigned)f2bf(Sr[1]) << 16);
    unsigned hi = (unsigned)f2bf(Sr[2]) | ((unsigned)f2bf(Sr[3]) << 16);
    uint2 pp; pp.x = lo; pp.y = hi;
    *(uint2*)&sIn[rowoff + f0] = pp;
  }

  const float hh = tg[1] - tg[0];
  const float sq = sqrtf(hh);
  float tcur = tg[0];

  // epilogue: relu + pack 4 bf16 + one b64 write; tile 12 keeps feats 200..207
  // untouched (200 holds the 1.0 bias-activation, 201+ stay zero)
#define EPI(DST, TL, ACC) {                                                   \
    int ff = (TL) * 16 + q * 4;                                               \
    if (!((TL) == 12 && q >= 2)){                                             \
      float v0 = fmaxf((ACC)[0], 0.f), v1 = fmaxf((ACC)[1], 0.f);             \
      float v2 = fmaxf((ACC)[2], 0.f), v3 = fmaxf((ACC)[3], 0.f);             \
      unsigned lo = (unsigned)f2bf(v0) | ((unsigned)f2bf(v1) << 16);          \
      unsigned hi = (unsigned)f2bf(v2) | ((unsigned)f2bf(v3) << 16);          \
      uint2 pp; pp.x = lo; pp.y = hi;                                         \
      *(uint2*)&(DST)[rowoff + ff] = pp;                                      \
    } }

#define HIDDEN(SRC, DST, WF) {                                                \
    f32x4 acc0 = {0.f,0.f,0.f,0.f}, acc1 = {0.f,0.f,0.f,0.f};                 \
    _Pragma("unroll")                                                         \
    for (int k = 0; k < 7; ++k){                                              \
      bf16x8 b = *(const bf16x8*)((SRC) + rowoff + k * 32 + q * 8);           \
      acc0 = MFMA16(WF[0][k], b, acc0);                                       \
      if (has2) acc1 = MFMA16(WF[1][k], b, acc1);                             \
    }                                                                         \
    EPI(DST, t0, acc0)                                                        \
    if (has2) EPI(DST, t1, acc1)                                              \
  }

  __syncthreads();                                  // init complete

  for (int t = 0; t < 100; ++t){
    // prefetches for this step (consumed at L4 / next iteration)
    f32x4 dwf = {0.f, 0.f, 0.f, 0.f};
    if (fvalid)
      dwf = *(const f32x4*)(dW + (blk * 16 + mr) * 10100 + t * 100 + f0);
    if (tid < 16) sIn[tid * FS + 100] = f2bf(tcur); // t row
    float tnext = tg[t + 1];
    __syncthreads();                                // (1) sIn complete

    // ---- L0: W0^T (LDS) x input ----
    {
      f32x4 acc0 = {0.f,0.f,0.f,0.f}, acc1 = {0.f,0.f,0.f,0.f};
#pragma unroll
      for (int k = 0; k < 4; ++k){
        bf16x8 b  = *(const bf16x8*)(sIn + rowoff + k * 32 + q * 8);
        bf16x8 a0 = *(const bf16x8*)(sW0 + ((t0 * 4 + k) * 64 + lane) * 8);
        acc0 = MFMA16(a0, b, acc0);
        if (has2){
          bf16x8 a1 = *(const bf16x8*)(sW0 + ((t1 * 4 + k) * 64 + lane) * 8);
          acc1 = MFMA16(a1, b, acc1);
        }
      }
      EPI(sA, t0, acc0)
      if (has2) EPI(sA, t1, acc1)
    }
    __syncthreads();                                // (2)
    HIDDEN(sA, sB, w1f)
    __syncthreads();                                // (3)
    HIDDEN(sB, sA, w2f)
    __syncthreads();                                // (4)
    HIDDEN(sA, sB, w3f)
    __syncthreads();                                // (5)

    // ---- L4: Wout^T (regs) x h3; update S/err; write next S-fragment ----
    if (hasOut){
      f32x4 a4 = {0.f, 0.f, 0.f, 0.f};
#pragma unroll
      for (int k = 0; k < 7; ++k){
        bf16x8 b = *(const bf16x8*)(sB + rowoff + k * 32 + q * 8);
        a4 = MFMA16(wo_f[k], b, a4);
      }
      if (fvalid){
#pragma unroll
        for (int i = 0; i < 4; ++i){
          float u = a4[i];                          // bias already included
          Er[i] += u * u * hh;
          Sr[i] += u * (hh + sq * dwf[i]);
        }
        unsigned lo = (unsigned)f2bf(Sr[0]) | ((unsigned)f2bf(Sr[1]) << 16);
        unsigned hi = (unsigned)f2bf(Sr[2]) | ((unsigned)f2bf(Sr[3]) << 16);
        uint2 pp; pp.x = lo; pp.y = hi;
        *(uint2*)&sIn[rowoff + f0] = pp;
      }
    }
    tcur = tnext;
  }

  // ---- output: err + S^2 ----
  if (fvalid){
    f32x4 o;
#pragma unroll
    for (int i = 0; i < 4; ++i) o[i] = Er[i] + Sr[i] * Sr[i];
    *(f32x4*)(outp + (blk * 16 + mr) * 100 + f0) = o;
  }
#undef HIDDEN
#undef EPI
}

// ---------------------------------------------------------------------------
extern "C" void kernel_launch(void* const* d_in, const int* in_sizes, int n_in,
                              void* d_out, int out_size, void* d_ws, size_t ws_size,
                              hipStream_t stream) {
  const float* S0 = (const float*)d_in[0];
  const float* tg = (const float*)d_in[1];
  const float* dW = (const float*)d_in[2];
  const float* W0 = (const float*)d_in[3];
  const float* b0 = (const float*)d_in[4];
  const float* W1 = (const float*)d_in[5];
  const float* b1 = (const float*)d_in[6];
  const float* W2 = (const float*)d_in[7];
  const float* b2 = (const float*)d_in[8];
  const float* W3 = (const float*)d_in[9];
  const float* b3 = (const float*)d_in[10];
  const float* Wo = (const float*)d_in[11];
  const float* bo = (const float*)d_in[12];
  unsigned short* Wp = (unsigned short*)d_ws;       // 382976 B used

  pack_w<<<(TOTE + 255) / 256, 256, 0, stream>>>(W0, b0, W1, b1, W2, b2, W3, b3,
                                                 Wo, bo, Wp);
  solver<<<256, 512, 0, stream>>>(S0, tg, dW, Wp, (float*)d_out);
}